// Round 8
// baseline (146.039 us; speedup 1.0000x reference)
//
#include <hip/hip_runtime.h>
#include <stdint.h>

#define BB 8
#define NN 2048
#define KK 32
#define FIN 256
#define FOUT 256
#define CC 512                 // 2*FOUT channels
#define MM (BB*NN)             // 16384 rows
#define RB 16                  // rows per gemm block
#define NBLK (MM/RB)           // 1024 gemm blocks (= 4 per CU)
#define LDA 264                // padded LDS row stride (ushorts)

typedef __attribute__((ext_vector_type(8))) short short8;
typedef __attribute__((ext_vector_type(4))) float f32x4;

__device__ __forceinline__ unsigned short f2bf(float f) {
    union { float f; unsigned u; } v; v.f = f;
    unsigned u = v.u;
    return (unsigned short)((u + 0x7FFFu + ((u >> 16) & 1u)) >> 16);  // RNE
}
__device__ __forceinline__ float bf2f(unsigned short s) {
    union { unsigned u; float f; } v; v.u = ((unsigned)s) << 16;
    return v.f;
}

// ---------------- K1: W pack (blocks [0,128)) + x->bf16 conv (blocks [128,2176))
__global__ void k_prep(const float* __restrict__ Wx, const float* __restrict__ Wxb,
                       const float* __restrict__ Wn, const float* __restrict__ Wnb,
                       const float* __restrict__ x,
                       unsigned short* __restrict__ Wc, float* __restrict__ bc,
                       unsigned short* __restrict__ xb) {
    const int blk = blockIdx.x;
    const int tid = threadIdx.x;
    if (blk < 128) {            // weight pack + bias concat
        int gid = blk * 256 + tid;                  // 4 elems each
        int e0 = gid * 4;
        int o = e0 >> 8, k = e0 & 255;
        const float* src = (o < FOUT) ? (Wx + o * FIN + k) : (Wn + (o - FOUT) * FIN + k);
        float4 v = *(const float4*)src;
        ushort4 p; p.x = f2bf(v.x); p.y = f2bf(v.y); p.z = f2bf(v.z); p.w = f2bf(v.w);
        *(ushort4*)(Wc + e0) = p;
        if (gid < 128) {
            int c0 = gid * 4;
            float4 bv = (c0 < FOUT) ? *(const float4*)(Wxb + c0)
                                    : *(const float4*)(Wnb + c0 - FOUT);
            *(float4*)(bc + c0) = bv;
        }
    } else {                    // x fp32 -> bf16, 8 elems/thread
        size_t gid = (size_t)(blk - 128) * 256 + tid;
        size_t e0 = gid * 8;
        float4 v0 = *(const float4*)(x + e0);
        float4 v1 = *(const float4*)(x + e0 + 4);
        ushort4 p0, p1;
        p0.x = f2bf(v0.x); p0.y = f2bf(v0.y); p0.z = f2bf(v0.z); p0.w = f2bf(v0.w);
        p1.x = f2bf(v1.x); p1.y = f2bf(v1.y); p1.z = f2bf(v1.z); p1.w = f2bf(v1.w);
        *(ushort4*)(xb + e0)     = p0;
        *(ushort4*)(xb + e0 + 4) = p1;
    }
}

// ---------------- K2: RB=16 tile, 512 threads (8 waves), 4 blocks/CU = 32 waves/CU
//                  self-stage + wide gather-mean + dual MFMA GEMM + bias
//                  + row L2-norm + ReLU + bf16 h + BN channel partials.
__global__ __launch_bounds__(512, 8)
void k_gemm(const unsigned short* __restrict__ xb, const int* __restrict__ idx,
            const unsigned short* __restrict__ Wc,
            const float* __restrict__ bc,
            unsigned short* __restrict__ h,
            float* __restrict__ psum, float* __restrict__ psq) {
    __shared__ unsigned short As[2][RB * LDA];   // [0]=self rows, [1]=neighbor rows
    __shared__ float sqpart[8][RB];
    __shared__ float rnorm[RB];

    const int bid  = blockIdx.x;
    const int tid  = threadIdx.x;
    const int w    = tid >> 6;          // 0..7
    const int lane = tid & 63;
    const int quad = lane >> 4;
    const int l16  = lane & 15;
    const int p    = lane >> 5;         // neighbor parity
    const int l32  = lane & 31;         // 8-channel group
    const int b    = bid & 7;
    const int n0   = (bid >> 3) * RB;
    const unsigned short* xbat = xb + (size_t)b * NN * FIN;
    const size_t r0g = (size_t)b * NN + n0;      // global output row base

    {   // self tile: 16 rows x 256 ch bf16 = 512 uint4; one per thread
        const uint4* gs = (const uint4*)(xbat + (size_t)n0 * FIN);
        uint4 v = gs[tid];                       // row=tid>>5, col8=tid&31
        *(uint4*)&As[0][(tid >> 5) * LDA + (tid & 31) * 8] = v;
    }
    {   // gather-mean: wave w -> local rows w*2, w*2+1; 2 neighbors per issue
        #pragma unroll
        for (int rr = 0; rr < 2; ++rr) {
            int lr = (w << 1) + rr;
            const int* ip = idx + (n0 + lr) * KK;      // wave-uniform
            const unsigned short* xp = xbat + l32 * 8;
            float ac[8] = {0.f,0.f,0.f,0.f,0.f,0.f,0.f,0.f};
            #pragma unroll 8
            for (int k = 0; k < 16; ++k) {
                int j = ip[(k << 1) | p];
                uint4 v = *(const uint4*)(xp + (size_t)j * FIN);
                const unsigned short* hv = (const unsigned short*)&v;
                #pragma unroll
                for (int c = 0; c < 8; ++c) ac[c] += bf2f(hv[c]);
            }
            #pragma unroll
            for (int c = 0; c < 8; ++c) ac[c] += __shfl_xor(ac[c], 32, 64);
            if (p == 0) {
                const float s = 1.0f / (float)KK;
                unsigned short o8[8];
                #pragma unroll
                for (int c = 0; c < 8; ++c) o8[c] = f2bf(ac[c] * s);
                *(uint4*)&As[1][lr * LDA + l32 * 8] = *(const uint4*)o8;
            }
        }
    }
    __syncthreads();

    const int half = w >> 2;                     // 0: self, 1: neighbor
    const unsigned short* A = As[half];
    const int cbg = half * 256 + (w & 3) * 64;   // wave's 64 output channels

    f32x4 acc[4];
    #pragma unroll
    for (int nt = 0; nt < 4; ++nt) acc[nt] = (f32x4){0.f, 0.f, 0.f, 0.f};

    const unsigned short* Bp = Wc + (size_t)(cbg + l16) * FIN + quad * 8;  // B^T frag base
    const unsigned short* Ap = A + (size_t)l16 * LDA + quad * 8;

    #pragma unroll 2
    for (int k0 = 0; k0 < FIN; k0 += 32) {
        short8 a0 = *(const short8*)(Ap + k0);
        short8 bfr[4];
        #pragma unroll
        for (int nt = 0; nt < 4; ++nt)
            bfr[nt] = *(const short8*)(Bp + (size_t)nt * 16 * FIN + k0);
        #pragma unroll
        for (int nt = 0; nt < 4; ++nt)
            acc[nt] = __builtin_amdgcn_mfma_f32_16x16x32_bf16(a0, bfr[nt], acc[nt], 0, 0, 0);
    }

    // bias + per-row sum of squares (C/D layout: col=l16, row=quad*4+reg)
    float bcv[4];
    #pragma unroll
    for (int nt = 0; nt < 4; ++nt) bcv[nt] = bc[cbg + nt * 16 + l16];

    float rsq[4] = {0.f,0.f,0.f,0.f};
    #pragma unroll
    for (int nt = 0; nt < 4; ++nt)
        #pragma unroll
        for (int r = 0; r < 4; ++r) {
            float v = acc[nt][r] + bcv[nt];
            acc[nt][r] = v;
            rsq[r] += v * v;
        }
    #pragma unroll
    for (int off = 1; off < 16; off <<= 1)
        #pragma unroll
        for (int r = 0; r < 4; ++r)
            rsq[r] += __shfl_xor(rsq[r], off, 64);
    if (l16 == 0) {
        #pragma unroll
        for (int r = 0; r < 4; ++r)
            sqpart[w][quad * 4 + r] = rsq[r];
    }
    __syncthreads();
    if (tid < RB) {
        float tot = 0.f;
        #pragma unroll
        for (int i = 0; i < 8; ++i) tot += sqpart[i][tid];
        rnorm[tid] = 1.0f / fmaxf(sqrtf(tot), 1e-12f);
    }
    __syncthreads();

    // normalize + relu + h store (bf16) + channel partials
    float csum[4] = {0.f,0.f,0.f,0.f};
    float csq [4] = {0.f,0.f,0.f,0.f};
    #pragma unroll
    for (int r = 0; r < 4; ++r) {
        int row = quad * 4 + r;
        float rn = rnorm[row];
        unsigned short* hp = h + (r0g + row) * CC + cbg + l16;
        #pragma unroll
        for (int nt = 0; nt < 4; ++nt) {
            float v = fmaxf(acc[nt][r] * rn, 0.0f);
            hp[nt * 16] = f2bf(v);
            csum[nt] += v;
            csq [nt] += v * v;
        }
    }
    #pragma unroll
    for (int off = 16; off < 64; off <<= 1)
        #pragma unroll
        for (int nt = 0; nt < 4; ++nt) {
            csum[nt] += __shfl_xor(csum[nt], off, 64);
            csq [nt] += __shfl_xor(csq [nt], off, 64);
        }
    if (quad == 0 && p == 0) {
        #pragma unroll
        for (int nt = 0; nt < 4; ++nt) {
            int c = cbg + nt * 16 + l16;
            psum[(size_t)c * NBLK + bid] = csum[nt];
            psq [(size_t)c * NBLK + bid] = csq [nt];
        }
    }
}

// ---------------- K3: reduce BN partials (1024 per channel) -> scale/shift
__global__ void k_stats(const float* __restrict__ psum, const float* __restrict__ psq,
                        const float* __restrict__ gamma, const float* __restrict__ beta,
                        float* __restrict__ ss) {
    __shared__ float ps[4], pq[4];
    int c = blockIdx.x, t = threadIdx.x;
    float s = 0.f, q = 0.f;
    #pragma unroll
    for (int i = 0; i < 4; ++i) {
        s += psum[(size_t)c * NBLK + i * 256 + t];
        q += psq [(size_t)c * NBLK + i * 256 + t];
    }
    #pragma unroll
    for (int off = 32; off; off >>= 1) { s += __shfl_xor(s, off, 64); q += __shfl_xor(q, off, 64); }
    int w = t >> 6, lane = t & 63;
    if (lane == 0) { ps[w] = s; pq[w] = q; }
    __syncthreads();
    if (t == 0) {
        float S = ps[0] + ps[1] + ps[2] + ps[3];
        float Q = pq[0] + pq[1] + pq[2] + pq[3];
        const float inv = 1.0f / (float)MM;
        float mu  = S * inv;
        float var = fmaxf(Q * inv - mu * mu, 0.0f);
        float sc  = gamma[c] * rsqrtf(var + 1e-5f);
        ss[c]      = sc;
        ss[CC + c] = beta[c] - mu * sc;
    }
}

// ---------------- K4: BN apply, bf16 h -> fp32 out, 8 elems/thread
__global__ void k_apply(const unsigned short* __restrict__ h,
                        const float* __restrict__ ss,
                        float* __restrict__ out) {
    int gid = blockIdx.x * 256 + threadIdx.x;   // 8 elems/thread
    int c0 = (gid * 8) & (CC - 1);
    uint4 hv = ((const uint4*)h)[gid];          // 8 bf16
    const unsigned short* hs = (const unsigned short*)&hv;
    float4 sc0 = *(const float4*)(ss + c0);
    float4 sc1 = *(const float4*)(ss + c0 + 4);
    float4 sh0 = *(const float4*)(ss + CC + c0);
    float4 sh1 = *(const float4*)(ss + CC + c0 + 4);
    float4 o0, o1;
    o0.x = bf2f(hs[0]) * sc0.x + sh0.x;
    o0.y = bf2f(hs[1]) * sc0.y + sh0.y;
    o0.z = bf2f(hs[2]) * sc0.z + sh0.z;
    o0.w = bf2f(hs[3]) * sc0.w + sh0.w;
    o1.x = bf2f(hs[4]) * sc1.x + sh1.x;
    o1.y = bf2f(hs[5]) * sc1.y + sh1.y;
    o1.z = bf2f(hs[6]) * sc1.z + sh1.z;
    o1.w = bf2f(hs[7]) * sc1.w + sh1.w;
    ((float4*)out)[gid * 2]     = o0;
    ((float4*)out)[gid * 2 + 1] = o1;
}

extern "C" void kernel_launch(void* const* d_in, const int* in_sizes, int n_in,
                              void* d_out, int out_size, void* d_ws, size_t ws_size,
                              hipStream_t stream) {
    const float* x     = (const float*)d_in[0];
    const int*   idx   = (const int*)  d_in[1];
    const float* Wx_w  = (const float*)d_in[2];
    const float* Wx_b  = (const float*)d_in[3];
    const float* Wn_w  = (const float*)d_in[4];
    const float* Wn_b  = (const float*)d_in[5];
    const float* gamma = (const float*)d_in[6];
    const float* beta  = (const float*)d_in[7];
    float* out = (float*)d_out;

    char* p = (char*)d_ws;
    unsigned short* xb = (unsigned short*)p; p += (size_t)MM * FIN * 2;   // 8.4 MB
    unsigned short* Wc = (unsigned short*)p; p += (size_t)CC * FIN * 2;   // 256 KB
    float* bc          = (float*)p;          p += (size_t)CC * 4;         // 2 KB
    unsigned short* h  = (unsigned short*)p; p += (size_t)MM * CC * 2;    // 16.8 MB
    float* psum        = (float*)p;          p += (size_t)CC * NBLK * 4;  // 2 MB
    float* psq         = (float*)p;          p += (size_t)CC * NBLK * 4;  // 2 MB
    float* ss          = (float*)p;          p += (size_t)2 * CC * 4;     // 4 KB

    hipLaunchKernelGGL(k_prep,  dim3(2176), dim3(256), 0, stream,
                       Wx_w, Wx_b, Wn_w, Wn_b, x, Wc, bc, xb);
    hipLaunchKernelGGL(k_gemm,  dim3(NBLK), dim3(512), 0, stream, xb, idx, Wc, bc, h, psum, psq);
    hipLaunchKernelGGL(k_stats, dim3(CC),   dim3(256), 0, stream, psum, psq, gamma, beta, ss);
    hipLaunchKernelGGL(k_apply, dim3(4096), dim3(256), 0, stream, h, ss, out);
}

// Round 9
// 138.212 us; speedup vs baseline: 1.0566x; 1.0566x over previous
//
#include <hip/hip_runtime.h>
#include <stdint.h>

#define BB 8
#define NN 2048
#define KK 32
#define FIN 256
#define FOUT 256
#define CC 512                 // 2*FOUT channels
#define MM (BB*NN)             // 16384 rows
#define RB 32                  // rows per gemm tile (4 n x 8 b)
#define NBLK 512               // gemm blocks (NN/4)
#define LDA 264                // padded LDS row stride (ushorts)

typedef __attribute__((ext_vector_type(8))) short short8;
typedef __attribute__((ext_vector_type(4))) float f32x4;

__device__ __forceinline__ unsigned short f2bf(float f) {
    union { float f; unsigned u; } v; v.f = f;
    unsigned u = v.u;
    return (unsigned short)((u + 0x7FFFu + ((u >> 16) & 1u)) >> 16);  // RNE
}
__device__ __forceinline__ float bf2f(unsigned short s) {
    union { unsigned u; float f; } v; v.u = ((unsigned)s) << 16;
    return v.f;
}

// ---------------- K1: W pack (blocks [0,128)) + x->bf16 TRANSPOSED conv
// (blocks [128,2176)): x [B,N,F] fp32 -> xb_t [N,B,F] bf16.
__global__ void k_prep(const float* __restrict__ Wx, const float* __restrict__ Wxb,
                       const float* __restrict__ Wn, const float* __restrict__ Wnb,
                       const float* __restrict__ x,
                       unsigned short* __restrict__ Wc, float* __restrict__ bc,
                       unsigned short* __restrict__ xb_t) {
    const int blk = blockIdx.x;
    const int tid = threadIdx.x;
    if (blk < 128) {            // weight pack + bias concat
        int gid = blk * 256 + tid;                  // 4 elems each
        int e0 = gid * 4;
        int o = e0 >> 8, k = e0 & 255;
        const float* src = (o < FOUT) ? (Wx + o * FIN + k) : (Wn + (o - FOUT) * FIN + k);
        float4 v = *(const float4*)src;
        ushort4 p; p.x = f2bf(v.x); p.y = f2bf(v.y); p.z = f2bf(v.z); p.w = f2bf(v.w);
        *(ushort4*)(Wc + e0) = p;
        if (gid < 128) {
            int c0 = gid * 4;
            float4 bv = (c0 < FOUT) ? *(const float4*)(Wxb + c0)
                                    : *(const float4*)(Wnb + c0 - FOUT);
            *(float4*)(bc + c0) = bv;
        }
    } else {                    // transpose-convert: 8 elems/thread
        size_t gid = (size_t)(blk - 128) * 256 + tid;
        size_t e0 = gid * 8;                        // elem in [B,N,F] order
        int b = (int)(e0 >> 19);                    // /(NN*FIN)
        int n = (int)((e0 >> 8) & (NN - 1));
        int c = (int)(e0 & (FIN - 1));
        float4 v0 = *(const float4*)(x + e0);
        float4 v1 = *(const float4*)(x + e0 + 4);
        ushort4 p0, p1;
        p0.x = f2bf(v0.x); p0.y = f2bf(v0.y); p0.z = f2bf(v0.z); p0.w = f2bf(v0.w);
        p1.x = f2bf(v1.x); p1.y = f2bf(v1.y); p1.z = f2bf(v1.z); p1.w = f2bf(v1.w);
        unsigned short* dst = xb_t + ((size_t)n * BB + b) * FIN + c;
        *(ushort4*)dst       = p0;
        *(ushort4*)(dst + 4) = p1;
    }
}

// ---------------- K2: tile = 4 n x 8 batches (32 rows). Slab gather (idx shared
// across batches: one 4 KB read serves 8 rows) + dual MFMA GEMM + bias
// + row L2-norm + ReLU + bf16 h + BN channel partials.
__global__ __launch_bounds__(512, 4)
void k_gemm(const unsigned short* __restrict__ xb_t, const int* __restrict__ idx,
            const unsigned short* __restrict__ Wc,
            const float* __restrict__ bc,
            unsigned short* __restrict__ h,
            float* __restrict__ psum, float* __restrict__ psq) {
    __shared__ unsigned short As[2][RB * LDA];   // [0]=self rows, [1]=neighbor rows
    __shared__ float sqpart[8][RB];
    __shared__ float rnorm[RB];

    const int bid  = blockIdx.x;
    const int tid  = threadIdx.x;
    const int w    = tid >> 6;          // 0..7
    const int lane = tid & 63;
    const int quad = lane >> 4;
    const int l16  = lane & 15;
    const int n0   = bid * 4;

    {   // self tile: slabs n0..n0+3 = 8192 contiguous ushorts = 1024 uint4
        const uint4* gs = (const uint4*)(xb_t + (size_t)n0 * BB * FIN);
        #pragma unroll
        for (int i = 0; i < 2; ++i) {
            int e = tid + i * 512;               // row=(e*8)>>8=e>>5, col8=e&31
            *(uint4*)&As[0][(e >> 5) * LDA + (e & 31) * 8] = gs[e];
        }
    }
    {   // slab gather-mean: wave w -> n_local = w>>1, part = w&1 (batches part*4..+3)
        const int n_local = w >> 1;
        const int part    = w & 1;
        const int* ip = idx + (n0 + n_local) * KK;       // wave-uniform
        const unsigned short* sp = xb_t + part * (4 * FIN) + lane * 8;
        float ac0[8] = {0.f,0.f,0.f,0.f,0.f,0.f,0.f,0.f};
        float ac1[8] = {0.f,0.f,0.f,0.f,0.f,0.f,0.f,0.f};
        #pragma unroll 8
        for (int k = 0; k < KK; ++k) {
            const unsigned short* base = sp + (size_t)ip[k] * (BB * FIN);
            uint4 v0 = *(const uint4*)base;          // elems part*1024 + lane*8
            uint4 v1 = *(const uint4*)(base + 512);  // elems part*1024 + 512 + lane*8
            const unsigned short* h0 = (const unsigned short*)&v0;
            const unsigned short* h1 = (const unsigned short*)&v1;
            #pragma unroll
            for (int c = 0; c < 8; ++c) { ac0[c] += bf2f(h0[c]); ac1[c] += bf2f(h1[c]); }
        }
        const float s = 1.0f / (float)KK;
        unsigned short o0[8], o1[8];
        #pragma unroll
        for (int c = 0; c < 8; ++c) { o0[c] = f2bf(ac0[c] * s); o1[c] = f2bf(ac1[c] * s); }
        // lane covers batch part*4+(lane>>5) (o0) and part*4+2+(lane>>5) (o1), ch8 = lane&31
        int row0 = n_local * 8 + part * 4 + (lane >> 5);
        *(uint4*)&As[1][row0 * LDA + (lane & 31) * 8]       = *(const uint4*)o0;
        *(uint4*)&As[1][(row0 + 2) * LDA + (lane & 31) * 8] = *(const uint4*)o1;
    }
    __syncthreads();

    const int half = w >> 2;                     // 0: self/Wx-ch, 1: neighbor/Wn-ch
    const unsigned short* A = As[half];
    const int cbg = half * 256 + (w & 3) * 64;   // wave's 64 output channels

    f32x4 acc[2][4];
    #pragma unroll
    for (int mt = 0; mt < 2; ++mt)
        #pragma unroll
        for (int nt = 0; nt < 4; ++nt) acc[mt][nt] = (f32x4){0.f, 0.f, 0.f, 0.f};

    const unsigned short* Bp = Wc + (size_t)(cbg + l16) * FIN + quad * 8;  // B^T frag base
    const unsigned short* Ap = A + (size_t)l16 * LDA + quad * 8;

    #pragma unroll 2
    for (int k0 = 0; k0 < FIN; k0 += 32) {
        short8 a0 = *(const short8*)(Ap + k0);
        short8 a1 = *(const short8*)(Ap + 16 * LDA + k0);
        short8 bfr[4];
        #pragma unroll
        for (int nt = 0; nt < 4; ++nt)
            bfr[nt] = *(const short8*)(Bp + (size_t)nt * 16 * FIN + k0);
        #pragma unroll
        for (int nt = 0; nt < 4; ++nt) {
            acc[0][nt] = __builtin_amdgcn_mfma_f32_16x16x32_bf16(a0, bfr[nt], acc[0][nt], 0, 0, 0);
            acc[1][nt] = __builtin_amdgcn_mfma_f32_16x16x32_bf16(a1, bfr[nt], acc[1][nt], 0, 0, 0);
        }
    }

    // bias + per-row sum of squares (C/D layout: col=l16, row=quad*4+reg)
    float bcv[4];
    #pragma unroll
    for (int nt = 0; nt < 4; ++nt) bcv[nt] = bc[cbg + nt * 16 + l16];

    float rsq[2][4] = {{0.f,0.f,0.f,0.f},{0.f,0.f,0.f,0.f}};
    #pragma unroll
    for (int mt = 0; mt < 2; ++mt)
        #pragma unroll
        for (int nt = 0; nt < 4; ++nt)
            #pragma unroll
            for (int r = 0; r < 4; ++r) {
                float v = acc[mt][nt][r] + bcv[nt];
                acc[mt][nt][r] = v;
                rsq[mt][r] += v * v;
            }
    #pragma unroll
    for (int off = 1; off < 16; off <<= 1)
        #pragma unroll
        for (int mt = 0; mt < 2; ++mt)
            #pragma unroll
            for (int r = 0; r < 4; ++r)
                rsq[mt][r] += __shfl_xor(rsq[mt][r], off, 64);
    if (l16 == 0) {
        #pragma unroll
        for (int mt = 0; mt < 2; ++mt)
            #pragma unroll
            for (int r = 0; r < 4; ++r)
                sqpart[w][mt * 16 + quad * 4 + r] = rsq[mt][r];
    }
    __syncthreads();
    if (tid < RB) {
        float tot = 0.f;
        #pragma unroll
        for (int i = 0; i < 8; ++i) tot += sqpart[i][tid];
        rnorm[tid] = 1.0f / fmaxf(sqrtf(tot), 1e-12f);
    }
    __syncthreads();

    // normalize + relu + h store (bf16) + channel partials
    float csum[4] = {0.f,0.f,0.f,0.f};
    float csq [4] = {0.f,0.f,0.f,0.f};
    #pragma unroll
    for (int mt = 0; mt < 2; ++mt) {
        #pragma unroll
        for (int r = 0; r < 4; ++r) {
            int row = mt * 16 + quad * 4 + r;        // = n_local*8 + b
            float rn = rnorm[row];
            // global output row = b*NN + n0 + n_local
            unsigned short* hp = h + ((size_t)(row & 7) * NN + n0 + (row >> 3)) * CC + cbg + l16;
            #pragma unroll
            for (int nt = 0; nt < 4; ++nt) {
                float v = fmaxf(acc[mt][nt][r] * rn, 0.0f);
                hp[nt * 16] = f2bf(v);
                csum[nt] += v;
                csq [nt] += v * v;
            }
        }
    }
    #pragma unroll
    for (int off = 16; off < 64; off <<= 1)
        #pragma unroll
        for (int nt = 0; nt < 4; ++nt) {
            csum[nt] += __shfl_xor(csum[nt], off, 64);
            csq [nt] += __shfl_xor(csq [nt], off, 64);
        }
    if (quad == 0 && (lane >> 5) == 0) {
        #pragma unroll
        for (int nt = 0; nt < 4; ++nt) {
            int c = cbg + nt * 16 + l16;
            psum[(size_t)c * NBLK + bid] = csum[nt];
            psq [(size_t)c * NBLK + bid] = csq [nt];
        }
    }
}

// ---------------- K3: reduce BN partials (512 per channel) -> scale/shift
__global__ void k_stats(const float* __restrict__ psum, const float* __restrict__ psq,
                        const float* __restrict__ gamma, const float* __restrict__ beta,
                        float* __restrict__ ss) {
    __shared__ float ps[4], pq[4];
    int c = blockIdx.x, t = threadIdx.x;
    float s = psum[(size_t)c * NBLK + t] + psum[(size_t)c * NBLK + 256 + t];
    float q = psq [(size_t)c * NBLK + t] + psq [(size_t)c * NBLK + 256 + t];
    #pragma unroll
    for (int off = 32; off; off >>= 1) { s += __shfl_xor(s, off, 64); q += __shfl_xor(q, off, 64); }
    int w = t >> 6, lane = t & 63;
    if (lane == 0) { ps[w] = s; pq[w] = q; }
    __syncthreads();
    if (t == 0) {
        float S = ps[0] + ps[1] + ps[2] + ps[3];
        float Q = pq[0] + pq[1] + pq[2] + pq[3];
        const float inv = 1.0f / (float)MM;
        float mu  = S * inv;
        float var = fmaxf(Q * inv - mu * mu, 0.0f);
        float sc  = gamma[c] * rsqrtf(var + 1e-5f);
        ss[c]      = sc;
        ss[CC + c] = beta[c] - mu * sc;
    }
}

// ---------------- K4: BN apply, bf16 h -> fp32 out, 8 elems/thread
__global__ void k_apply(const unsigned short* __restrict__ h,
                        const float* __restrict__ ss,
                        float* __restrict__ out) {
    int gid = blockIdx.x * 256 + threadIdx.x;   // 8 elems/thread
    int c0 = (gid * 8) & (CC - 1);
    uint4 hv = ((const uint4*)h)[gid];          // 8 bf16
    const unsigned short* hs = (const unsigned short*)&hv;
    float4 sc0 = *(const float4*)(ss + c0);
    float4 sc1 = *(const float4*)(ss + c0 + 4);
    float4 sh0 = *(const float4*)(ss + CC + c0);
    float4 sh1 = *(const float4*)(ss + CC + c0 + 4);
    float4 o0, o1;
    o0.x = bf2f(hs[0]) * sc0.x + sh0.x;
    o0.y = bf2f(hs[1]) * sc0.y + sh0.y;
    o0.z = bf2f(hs[2]) * sc0.z + sh0.z;
    o0.w = bf2f(hs[3]) * sc0.w + sh0.w;
    o1.x = bf2f(hs[4]) * sc1.x + sh1.x;
    o1.y = bf2f(hs[5]) * sc1.y + sh1.y;
    o1.z = bf2f(hs[6]) * sc1.z + sh1.z;
    o1.w = bf2f(hs[7]) * sc1.w + sh1.w;
    ((float4*)out)[gid * 2]     = o0;
    ((float4*)out)[gid * 2 + 1] = o1;
}

extern "C" void kernel_launch(void* const* d_in, const int* in_sizes, int n_in,
                              void* d_out, int out_size, void* d_ws, size_t ws_size,
                              hipStream_t stream) {
    const float* x     = (const float*)d_in[0];
    const int*   idx   = (const int*)  d_in[1];
    const float* Wx_w  = (const float*)d_in[2];
    const float* Wx_b  = (const float*)d_in[3];
    const float* Wn_w  = (const float*)d_in[4];
    const float* Wn_b  = (const float*)d_in[5];
    const float* gamma = (const float*)d_in[6];
    const float* beta  = (const float*)d_in[7];
    float* out = (float*)d_out;

    char* p = (char*)d_ws;
    unsigned short* xb_t = (unsigned short*)p; p += (size_t)MM * FIN * 2;   // 8.4 MB
    unsigned short* Wc   = (unsigned short*)p; p += (size_t)CC * FIN * 2;   // 256 KB
    float* bc            = (float*)p;          p += (size_t)CC * 4;         // 2 KB
    unsigned short* h    = (unsigned short*)p; p += (size_t)MM * CC * 2;    // 16.8 MB
    float* psum          = (float*)p;          p += (size_t)CC * NBLK * 4;  // 1 MB
    float* psq           = (float*)p;          p += (size_t)CC * NBLK * 4;  // 1 MB
    float* ss            = (float*)p;          p += (size_t)2 * CC * 4;     // 4 KB

    hipLaunchKernelGGL(k_prep,  dim3(2176), dim3(256), 0, stream,
                       Wx_w, Wx_b, Wn_w, Wn_b, x, Wc, bc, xb_t);
    hipLaunchKernelGGL(k_gemm,  dim3(NBLK), dim3(512), 0, stream, xb_t, idx, Wc, bc, h, psum, psq);
    hipLaunchKernelGGL(k_stats, dim3(CC),   dim3(256), 0, stream, psum, psq, gamma, beta, ss);
    hipLaunchKernelGGL(k_apply, dim3(4096), dim3(256), 0, stream, h, ss, out);
}

// Round 10
// 129.248 us; speedup vs baseline: 1.1299x; 1.0694x over previous
//
#include <hip/hip_runtime.h>
#include <stdint.h>

#define BB 8
#define NN 2048
#define KK 32
#define FIN 256
#define FOUT 256
#define CC 512                 // 2*FOUT channels
#define MM (BB*NN)             // 16384 rows
#define RB 32                  // rows per gemm block
#define NBLK (MM/RB)           // 512 gemm blocks (= 2 per CU)
#define LDA 264                // padded LDS row stride (ushorts)

typedef __attribute__((ext_vector_type(8))) short short8;
typedef __attribute__((ext_vector_type(4))) float f32x4;

__device__ __forceinline__ unsigned short f2bf(float f) {
    union { float f; unsigned u; } v; v.f = f;
    unsigned u = v.u;
    return (unsigned short)((u + 0x7FFFu + ((u >> 16) & 1u)) >> 16);  // RNE
}
__device__ __forceinline__ float bf2f(unsigned short s) {
    union { unsigned u; float f; } v; v.u = ((unsigned)s) << 16;
    return v.f;
}

// ---------------- K1: W pack (blocks [0,128)) + x->bf16 conv (blocks [128,2176))
// Batch-sliced xb layout [B][N][F]: per-XCD gather working set = 1 MB slice,
// L2-resident via bid&7 pinning in k_gemm (verified R6: FETCH 6.3 MB).
__global__ void k_prep(const float* __restrict__ Wx, const float* __restrict__ Wxb,
                       const float* __restrict__ Wn, const float* __restrict__ Wnb,
                       const float* __restrict__ x,
                       unsigned short* __restrict__ Wc, float* __restrict__ bc,
                       unsigned short* __restrict__ xb) {
    const int blk = blockIdx.x;
    const int tid = threadIdx.x;
    if (blk < 128) {            // weight pack + bias concat
        int gid = blk * 256 + tid;                  // 4 elems each
        int e0 = gid * 4;
        int o = e0 >> 8, k = e0 & 255;
        const float* src = (o < FOUT) ? (Wx + o * FIN + k) : (Wn + (o - FOUT) * FIN + k);
        float4 v = *(const float4*)src;
        ushort4 p; p.x = f2bf(v.x); p.y = f2bf(v.y); p.z = f2bf(v.z); p.w = f2bf(v.w);
        *(ushort4*)(Wc + e0) = p;
        if (gid < 128) {
            int c0 = gid * 4;
            float4 bv = (c0 < FOUT) ? *(const float4*)(Wxb + c0)
                                    : *(const float4*)(Wnb + c0 - FOUT);
            *(float4*)(bc + c0) = bv;
        }
    } else {                    // x fp32 -> bf16, 8 elems/thread
        size_t gid = (size_t)(blk - 128) * 256 + tid;
        size_t e0 = gid * 8;
        float4 v0 = *(const float4*)(x + e0);
        float4 v1 = *(const float4*)(x + e0 + 4);
        ushort4 p0, p1;
        p0.x = f2bf(v0.x); p0.y = f2bf(v0.y); p0.z = f2bf(v0.z); p0.w = f2bf(v0.w);
        p1.x = f2bf(v1.x); p1.y = f2bf(v1.y); p1.z = f2bf(v1.z); p1.w = f2bf(v1.w);
        *(ushort4*)(xb + e0)     = p0;
        *(ushort4*)(xb + e0 + 4) = p1;
    }
}

// ---------------- K2: 512 threads (8 waves), RB=32: self-stage + ILP gather-mean
//                  + dual MFMA GEMM + bias + row L2-norm + ReLU + bf16 h
//                  + BN channel partials.
// Gather: k-outer loop, 4 rows inner -> 4 independent uint4 load streams/wave
// (x unroll 2 = 8 in flight), 2 neighbors per load via lane parity.
__global__ __launch_bounds__(512, 4)
void k_gemm(const unsigned short* __restrict__ xb, const int* __restrict__ idx,
            const unsigned short* __restrict__ Wc,
            const float* __restrict__ bc,
            unsigned short* __restrict__ h,
            float* __restrict__ psum, float* __restrict__ psq) {
    __shared__ unsigned short As[2][RB * LDA];   // [0]=self rows, [1]=neighbor rows
    __shared__ float sqpart[8][RB];
    __shared__ float rnorm[RB];

    const int bid  = blockIdx.x;
    const int tid  = threadIdx.x;
    const int w    = tid >> 6;          // 0..7
    const int lane = tid & 63;
    const int quad = lane >> 4;
    const int l16  = lane & 15;
    const int p    = lane >> 5;         // neighbor parity
    const int l32  = lane & 31;         // 8-channel group
    const int b    = bid & 7;
    const int n0   = (bid >> 3) * RB;
    const unsigned short* xbat = xb + (size_t)b * NN * FIN;
    const size_t r0g = (size_t)b * NN + n0;      // global output row base

    {   // self tile: 32 rows x 256 ch bf16 = 1024 uint4; 512 thr x 2
        const uint4* gs = (const uint4*)(xbat + (size_t)n0 * FIN);
        #pragma unroll
        for (int i = 0; i < 2; ++i) {
            int e = tid + i * 512;               // row=e>>5, col8=e&31
            *(uint4*)&As[0][(e >> 5) * LDA + (e & 31) * 8] = gs[e];
        }
    }
    {   // gather-mean: wave w -> rows w*4..w*4+3; k-outer for cross-row ILP
        const int* ip = idx + (n0 + (w << 2)) * KK;    // 4 rows' index lists
        const unsigned short* xp = xbat + l32 * 8;
        float ac[4][8];
        #pragma unroll
        for (int rr = 0; rr < 4; ++rr)
            #pragma unroll
            for (int c = 0; c < 8; ++c) ac[rr][c] = 0.f;

        #pragma unroll 2
        for (int k = 0; k < 16; ++k) {
            int kk = (k << 1) | p;
            int j0 = ip[0 * KK + kk];
            int j1 = ip[1 * KK + kk];
            int j2 = ip[2 * KK + kk];
            int j3 = ip[3 * KK + kk];
            uint4 v0 = *(const uint4*)(xp + (size_t)j0 * FIN);
            uint4 v1 = *(const uint4*)(xp + (size_t)j1 * FIN);
            uint4 v2 = *(const uint4*)(xp + (size_t)j2 * FIN);
            uint4 v3 = *(const uint4*)(xp + (size_t)j3 * FIN);
            const unsigned short* h0 = (const unsigned short*)&v0;
            const unsigned short* h1 = (const unsigned short*)&v1;
            const unsigned short* h2 = (const unsigned short*)&v2;
            const unsigned short* h3 = (const unsigned short*)&v3;
            #pragma unroll
            for (int c = 0; c < 8; ++c) {
                ac[0][c] += bf2f(h0[c]);
                ac[1][c] += bf2f(h1[c]);
                ac[2][c] += bf2f(h2[c]);
                ac[3][c] += bf2f(h3[c]);
            }
        }
        const float s = 1.0f / (float)KK;
        #pragma unroll
        for (int rr = 0; rr < 4; ++rr) {
            #pragma unroll
            for (int c = 0; c < 8; ++c) ac[rr][c] += __shfl_xor(ac[rr][c], 32, 64);
            if (p == 0) {
                unsigned short o8[8];
                #pragma unroll
                for (int c = 0; c < 8; ++c) o8[c] = f2bf(ac[rr][c] * s);
                *(uint4*)&As[1][((w << 2) + rr) * LDA + l32 * 8] = *(const uint4*)o8;
            }
        }
    }
    __syncthreads();

    const int half = w >> 2;                     // 0: self, 1: neighbor
    const unsigned short* A = As[half];
    const int cbg = half * 256 + (w & 3) * 64;   // wave's 64 output channels

    f32x4 acc[2][4];
    #pragma unroll
    for (int mt = 0; mt < 2; ++mt)
        #pragma unroll
        for (int nt = 0; nt < 4; ++nt) acc[mt][nt] = (f32x4){0.f, 0.f, 0.f, 0.f};

    const unsigned short* Bp = Wc + (size_t)(cbg + l16) * FIN + quad * 8;  // B^T frag base
    const unsigned short* Ap = A + (size_t)l16 * LDA + quad * 8;

    #pragma unroll 2
    for (int k0 = 0; k0 < FIN; k0 += 32) {
        short8 a0 = *(const short8*)(Ap + k0);
        short8 a1 = *(const short8*)(Ap + 16 * LDA + k0);
        short8 bfr[4];
        #pragma unroll
        for (int nt = 0; nt < 4; ++nt)
            bfr[nt] = *(const short8*)(Bp + (size_t)nt * 16 * FIN + k0);
        #pragma unroll
        for (int nt = 0; nt < 4; ++nt) {
            acc[0][nt] = __builtin_amdgcn_mfma_f32_16x16x32_bf16(a0, bfr[nt], acc[0][nt], 0, 0, 0);
            acc[1][nt] = __builtin_amdgcn_mfma_f32_16x16x32_bf16(a1, bfr[nt], acc[1][nt], 0, 0, 0);
        }
    }

    // bias + per-row sum of squares (C/D layout: col=l16, row=quad*4+reg)
    float bcv[4];
    #pragma unroll
    for (int nt = 0; nt < 4; ++nt) bcv[nt] = bc[cbg + nt * 16 + l16];

    float rsq[2][4] = {{0.f,0.f,0.f,0.f},{0.f,0.f,0.f,0.f}};
    #pragma unroll
    for (int mt = 0; mt < 2; ++mt)
        #pragma unroll
        for (int nt = 0; nt < 4; ++nt)
            #pragma unroll
            for (int r = 0; r < 4; ++r) {
                float v = acc[mt][nt][r] + bcv[nt];
                acc[mt][nt][r] = v;
                rsq[mt][r] += v * v;
            }
    #pragma unroll
    for (int off = 1; off < 16; off <<= 1)
        #pragma unroll
        for (int mt = 0; mt < 2; ++mt)
            #pragma unroll
            for (int r = 0; r < 4; ++r)
                rsq[mt][r] += __shfl_xor(rsq[mt][r], off, 64);
    if (l16 == 0) {
        #pragma unroll
        for (int mt = 0; mt < 2; ++mt)
            #pragma unroll
            for (int r = 0; r < 4; ++r)
                sqpart[w][mt * 16 + quad * 4 + r] = rsq[mt][r];
    }
    __syncthreads();
    if (tid < RB) {
        float tot = 0.f;
        #pragma unroll
        for (int i = 0; i < 8; ++i) tot += sqpart[i][tid];
        rnorm[tid] = 1.0f / fmaxf(sqrtf(tot), 1e-12f);
    }
    __syncthreads();

    // normalize + relu + h store (bf16) + channel partials
    float csum[4] = {0.f,0.f,0.f,0.f};
    float csq [4] = {0.f,0.f,0.f,0.f};
    #pragma unroll
    for (int mt = 0; mt < 2; ++mt) {
        #pragma unroll
        for (int r = 0; r < 4; ++r) {
            int row = mt * 16 + quad * 4 + r;
            float rn = rnorm[row];
            unsigned short* hp = h + (r0g + row) * CC + cbg + l16;
            #pragma unroll
            for (int nt = 0; nt < 4; ++nt) {
                float v = fmaxf(acc[mt][nt][r] * rn, 0.0f);
                hp[nt * 16] = f2bf(v);
                csum[nt] += v;
                csq [nt] += v * v;
            }
        }
    }
    #pragma unroll
    for (int off = 16; off < 64; off <<= 1)
        #pragma unroll
        for (int nt = 0; nt < 4; ++nt) {
            csum[nt] += __shfl_xor(csum[nt], off, 64);
            csq [nt] += __shfl_xor(csq [nt], off, 64);
        }
    if (quad == 0 && p == 0) {
        #pragma unroll
        for (int nt = 0; nt < 4; ++nt) {
            int c = cbg + nt * 16 + l16;
            psum[(size_t)c * NBLK + bid] = csum[nt];
            psq [(size_t)c * NBLK + bid] = csq [nt];
        }
    }
}

// ---------------- K3: reduce BN partials (512 per channel) -> scale/shift
__global__ void k_stats(const float* __restrict__ psum, const float* __restrict__ psq,
                        const float* __restrict__ gamma, const float* __restrict__ beta,
                        float* __restrict__ ss) {
    __shared__ float ps[4], pq[4];
    int c = blockIdx.x, t = threadIdx.x;
    float s = psum[(size_t)c * NBLK + t] + psum[(size_t)c * NBLK + 256 + t];
    float q = psq [(size_t)c * NBLK + t] + psq [(size_t)c * NBLK + 256 + t];
    #pragma unroll
    for (int off = 32; off; off >>= 1) { s += __shfl_xor(s, off, 64); q += __shfl_xor(q, off, 64); }
    int w = t >> 6, lane = t & 63;
    if (lane == 0) { ps[w] = s; pq[w] = q; }
    __syncthreads();
    if (t == 0) {
        float S = ps[0] + ps[1] + ps[2] + ps[3];
        float Q = pq[0] + pq[1] + pq[2] + pq[3];
        const float inv = 1.0f / (float)MM;
        float mu  = S * inv;
        float var = fmaxf(Q * inv - mu * mu, 0.0f);
        float sc  = gamma[c] * rsqrtf(var + 1e-5f);
        ss[c]      = sc;
        ss[CC + c] = beta[c] - mu * sc;
    }
}

// ---------------- K4: BN apply, bf16 h -> fp32 out, 8 elems/thread
__global__ void k_apply(const unsigned short* __restrict__ h,
                        const float* __restrict__ ss,
                        float* __restrict__ out) {
    int gid = blockIdx.x * 256 + threadIdx.x;   // 8 elems/thread
    int c0 = (gid * 8) & (CC - 1);
    uint4 hv = ((const uint4*)h)[gid];          // 8 bf16
    const unsigned short* hs = (const unsigned short*)&hv;
    float4 sc0 = *(const float4*)(ss + c0);
    float4 sc1 = *(const float4*)(ss + c0 + 4);
    float4 sh0 = *(const float4*)(ss + CC + c0);
    float4 sh1 = *(const float4*)(ss + CC + c0 + 4);
    float4 o0, o1;
    o0.x = bf2f(hs[0]) * sc0.x + sh0.x;
    o0.y = bf2f(hs[1]) * sc0.y + sh0.y;
    o0.z = bf2f(hs[2]) * sc0.z + sh0.z;
    o0.w = bf2f(hs[3]) * sc0.w + sh0.w;
    o1.x = bf2f(hs[4]) * sc1.x + sh1.x;
    o1.y = bf2f(hs[5]) * sc1.y + sh1.y;
    o1.z = bf2f(hs[6]) * sc1.z + sh1.z;
    o1.w = bf2f(hs[7]) * sc1.w + sh1.w;
    ((float4*)out)[gid * 2]     = o0;
    ((float4*)out)[gid * 2 + 1] = o1;
}

extern "C" void kernel_launch(void* const* d_in, const int* in_sizes, int n_in,
                              void* d_out, int out_size, void* d_ws, size_t ws_size,
                              hipStream_t stream) {
    const float* x     = (const float*)d_in[0];
    const int*   idx   = (const int*)  d_in[1];
    const float* Wx_w  = (const float*)d_in[2];
    const float* Wx_b  = (const float*)d_in[3];
    const float* Wn_w  = (const float*)d_in[4];
    const float* Wn_b  = (const float*)d_in[5];
    const float* gamma = (const float*)d_in[6];
    const float* beta  = (const float*)d_in[7];
    float* out = (float*)d_out;

    char* p = (char*)d_ws;
    unsigned short* xb = (unsigned short*)p; p += (size_t)MM * FIN * 2;   // 8.4 MB
    unsigned short* Wc = (unsigned short*)p; p += (size_t)CC * FIN * 2;   // 256 KB
    float* bc          = (float*)p;          p += (size_t)CC * 4;         // 2 KB
    unsigned short* h  = (unsigned short*)p; p += (size_t)MM * CC * 2;    // 16.8 MB
    float* psum        = (float*)p;          p += (size_t)CC * NBLK * 4;  // 1 MB
    float* psq         = (float*)p;          p += (size_t)CC * NBLK * 4;  // 1 MB
    float* ss          = (float*)p;          p += (size_t)2 * CC * 4;     // 4 KB

    hipLaunchKernelGGL(k_prep,  dim3(2176), dim3(256), 0, stream,
                       Wx_w, Wx_b, Wn_w, Wn_b, x, Wc, bc, xb);
    hipLaunchKernelGGL(k_gemm,  dim3(NBLK), dim3(512), 0, stream, xb, idx, Wc, bc, h, psum, psq);
    hipLaunchKernelGGL(k_stats, dim3(CC),   dim3(256), 0, stream, psum, psq, gamma, beta, ss);
    hipLaunchKernelGGL(k_apply, dim3(4096), dim3(256), 0, stream, h, ss, out);
}

// Round 11
// 127.512 us; speedup vs baseline: 1.1453x; 1.0136x over previous
//
#include <hip/hip_runtime.h>
#include <stdint.h>

#define BB 8
#define NN 2048
#define KK 32
#define FIN 256
#define FOUT 256
#define CC 512                 // 2*FOUT channels
#define MM (BB*NN)             // 16384 rows
#define RB 32                  // rows per gemm block
#define NBLK (MM/RB)           // 512 gemm blocks (= 2 per CU)
#define LDA 264                // padded LDS row stride (ushorts)

typedef __attribute__((ext_vector_type(8))) short short8;
typedef __attribute__((ext_vector_type(4))) float f32x4;
typedef __attribute__((ext_vector_type(2))) float f32x2;

__device__ __forceinline__ unsigned short f2bf(float f) {
    union { float f; unsigned u; } v; v.f = f;
    unsigned u = v.u;
    return (unsigned short)((u + 0x7FFFu + ((u >> 16) & 1u)) >> 16);  // RNE
}
__device__ __forceinline__ float bf2f(unsigned short s) {
    union { unsigned u; float f; } v; v.u = ((unsigned)s) << 16;
    return v.f;
}
// 2 bf16 in one dword -> float2 {lo, hi}; hi needs no shift (AND only)
__device__ __forceinline__ f32x2 bfpair(unsigned u) {
    union { unsigned u; float f; } lo, hi;
    lo.u = u << 16;
    hi.u = u & 0xFFFF0000u;
    return (f32x2){lo.f, hi.f};
}

// ---------------- K1: W pack (blocks [0,128)) + x->bf16 conv (blocks [128,2176))
// Batch-sliced xb layout [B][N][F]: per-XCD gather working set = 1 MB slice,
// L2-resident via bid&7 pinning in k_gemm (verified R6: FETCH 6.3 MB).
__global__ void k_prep(const float* __restrict__ Wx, const float* __restrict__ Wxb,
                       const float* __restrict__ Wn, const float* __restrict__ Wnb,
                       const float* __restrict__ x,
                       unsigned short* __restrict__ Wc, float* __restrict__ bc,
                       unsigned short* __restrict__ xb) {
    const int blk = blockIdx.x;
    const int tid = threadIdx.x;
    if (blk < 128) {            // weight pack + bias concat
        int gid = blk * 256 + tid;                  // 4 elems each
        int e0 = gid * 4;
        int o = e0 >> 8, k = e0 & 255;
        const float* src = (o < FOUT) ? (Wx + o * FIN + k) : (Wn + (o - FOUT) * FIN + k);
        float4 v = *(const float4*)src;
        ushort4 p; p.x = f2bf(v.x); p.y = f2bf(v.y); p.z = f2bf(v.z); p.w = f2bf(v.w);
        *(ushort4*)(Wc + e0) = p;
        if (gid < 128) {
            int c0 = gid * 4;
            float4 bv = (c0 < FOUT) ? *(const float4*)(Wxb + c0)
                                    : *(const float4*)(Wnb + c0 - FOUT);
            *(float4*)(bc + c0) = bv;
        }
    } else {                    // x fp32 -> bf16, 8 elems/thread
        size_t gid = (size_t)(blk - 128) * 256 + tid;
        size_t e0 = gid * 8;
        float4 v0 = *(const float4*)(x + e0);
        float4 v1 = *(const float4*)(x + e0 + 4);
        ushort4 p0, p1;
        p0.x = f2bf(v0.x); p0.y = f2bf(v0.y); p0.z = f2bf(v0.z); p0.w = f2bf(v0.w);
        p1.x = f2bf(v1.x); p1.y = f2bf(v1.y); p1.z = f2bf(v1.z); p1.w = f2bf(v1.w);
        *(ushort4*)(xb + e0)     = p0;
        *(ushort4*)(xb + e0 + 4) = p1;
    }
}

// ---------------- K2: 512 threads (8 waves), RB=32: self-stage + ILP gather-mean
//                  (packed-pair fp32 accumulate) + dual MFMA GEMM + bias
//                  + row L2-norm + ReLU + bf16 h + BN channel partials.
__global__ __launch_bounds__(512, 4)
void k_gemm(const unsigned short* __restrict__ xb, const int* __restrict__ idx,
            const unsigned short* __restrict__ Wc,
            const float* __restrict__ bc,
            unsigned short* __restrict__ h,
            float* __restrict__ psum, float* __restrict__ psq) {
    __shared__ unsigned short As[2][RB * LDA];   // [0]=self rows, [1]=neighbor rows
    __shared__ float sqpart[8][RB];
    __shared__ float rnorm[RB];

    const int bid  = blockIdx.x;
    const int tid  = threadIdx.x;
    const int w    = tid >> 6;          // 0..7
    const int lane = tid & 63;
    const int quad = lane >> 4;
    const int l16  = lane & 15;
    const int p    = lane >> 5;         // neighbor parity
    const int l32  = lane & 31;         // 8-channel group
    const int b    = bid & 7;
    const int n0   = (bid >> 3) * RB;
    const unsigned short* xbat = xb + (size_t)b * NN * FIN;
    const size_t r0g = (size_t)b * NN + n0;      // global output row base

    {   // self tile: 32 rows x 256 ch bf16 = 1024 uint4; 512 thr x 2
        const uint4* gs = (const uint4*)(xbat + (size_t)n0 * FIN);
        #pragma unroll
        for (int i = 0; i < 2; ++i) {
            int e = tid + i * 512;               // row=e>>5, col8=e&31
            *(uint4*)&As[0][(e >> 5) * LDA + (e & 31) * 8] = gs[e];
        }
    }
    {   // gather-mean: wave w -> rows w*4..w*4+3; k-outer for cross-row ILP;
        // packed {lo,hi} fp32 accumulation -> v_pk_add_f32
        const int* ip = idx + (n0 + (w << 2)) * KK;    // 4 rows' index lists
        const unsigned short* xp = xbat + l32 * 8;
        f32x2 ac[4][4];                                // [row][pair of channels]
        #pragma unroll
        for (int rr = 0; rr < 4; ++rr)
            #pragma unroll
            for (int c = 0; c < 4; ++c) ac[rr][c] = (f32x2){0.f, 0.f};

        #pragma unroll 2
        for (int k = 0; k < 16; ++k) {
            int kk = (k << 1) | p;
            int j0 = ip[0 * KK + kk];
            int j1 = ip[1 * KK + kk];
            int j2 = ip[2 * KK + kk];
            int j3 = ip[3 * KK + kk];
            uint4 v0 = *(const uint4*)(xp + (size_t)j0 * FIN);
            uint4 v1 = *(const uint4*)(xp + (size_t)j1 * FIN);
            uint4 v2 = *(const uint4*)(xp + (size_t)j2 * FIN);
            uint4 v3 = *(const uint4*)(xp + (size_t)j3 * FIN);
            const unsigned* u0 = (const unsigned*)&v0;
            const unsigned* u1 = (const unsigned*)&v1;
            const unsigned* u2 = (const unsigned*)&v2;
            const unsigned* u3 = (const unsigned*)&v3;
            #pragma unroll
            for (int c = 0; c < 4; ++c) {
                ac[0][c] += bfpair(u0[c]);
                ac[1][c] += bfpair(u1[c]);
                ac[2][c] += bfpair(u2[c]);
                ac[3][c] += bfpair(u3[c]);
            }
        }
        const float s = 1.0f / (float)KK;
        #pragma unroll
        for (int rr = 0; rr < 4; ++rr) {
            #pragma unroll
            for (int c = 0; c < 4; ++c) {
                ac[rr][c][0] += __shfl_xor(ac[rr][c][0], 32, 64);
                ac[rr][c][1] += __shfl_xor(ac[rr][c][1], 32, 64);
            }
            if (p == 0) {
                unsigned short o8[8];
                #pragma unroll
                for (int c = 0; c < 4; ++c) {
                    o8[2 * c]     = f2bf(ac[rr][c][0] * s);   // lo = even channel
                    o8[2 * c + 1] = f2bf(ac[rr][c][1] * s);   // hi = odd channel
                }
                *(uint4*)&As[1][((w << 2) + rr) * LDA + l32 * 8] = *(const uint4*)o8;
            }
        }
    }
    __syncthreads();

    const int half = w >> 2;                     // 0: self, 1: neighbor
    const unsigned short* A = As[half];
    const int cbg = half * 256 + (w & 3) * 64;   // wave's 64 output channels

    f32x4 acc[2][4];
    #pragma unroll
    for (int mt = 0; mt < 2; ++mt)
        #pragma unroll
        for (int nt = 0; nt < 4; ++nt) acc[mt][nt] = (f32x4){0.f, 0.f, 0.f, 0.f};

    const unsigned short* Bp = Wc + (size_t)(cbg + l16) * FIN + quad * 8;  // B^T frag base
    const unsigned short* Ap = A + (size_t)l16 * LDA + quad * 8;

    #pragma unroll 2
    for (int k0 = 0; k0 < FIN; k0 += 32) {
        short8 a0 = *(const short8*)(Ap + k0);
        short8 a1 = *(const short8*)(Ap + 16 * LDA + k0);
        short8 bfr[4];
        #pragma unroll
        for (int nt = 0; nt < 4; ++nt)
            bfr[nt] = *(const short8*)(Bp + (size_t)nt * 16 * FIN + k0);
        #pragma unroll
        for (int nt = 0; nt < 4; ++nt) {
            acc[0][nt] = __builtin_amdgcn_mfma_f32_16x16x32_bf16(a0, bfr[nt], acc[0][nt], 0, 0, 0);
            acc[1][nt] = __builtin_amdgcn_mfma_f32_16x16x32_bf16(a1, bfr[nt], acc[1][nt], 0, 0, 0);
        }
    }

    // bias + per-row sum of squares (C/D layout: col=l16, row=quad*4+reg)
    float bcv[4];
    #pragma unroll
    for (int nt = 0; nt < 4; ++nt) bcv[nt] = bc[cbg + nt * 16 + l16];

    float rsq[2][4] = {{0.f,0.f,0.f,0.f},{0.f,0.f,0.f,0.f}};
    #pragma unroll
    for (int mt = 0; mt < 2; ++mt)
        #pragma unroll
        for (int nt = 0; nt < 4; ++nt)
            #pragma unroll
            for (int r = 0; r < 4; ++r) {
                float v = acc[mt][nt][r] + bcv[nt];
                acc[mt][nt][r] = v;
                rsq[mt][r] += v * v;
            }
    #pragma unroll
    for (int off = 1; off < 16; off <<= 1)
        #pragma unroll
        for (int mt = 0; mt < 2; ++mt)
            #pragma unroll
            for (int r = 0; r < 4; ++r)
                rsq[mt][r] += __shfl_xor(rsq[mt][r], off, 64);
    if (l16 == 0) {
        #pragma unroll
        for (int mt = 0; mt < 2; ++mt)
            #pragma unroll
            for (int r = 0; r < 4; ++r)
                sqpart[w][mt * 16 + quad * 4 + r] = rsq[mt][r];
    }
    __syncthreads();
    if (tid < RB) {
        float tot = 0.f;
        #pragma unroll
        for (int i = 0; i < 8; ++i) tot += sqpart[i][tid];
        rnorm[tid] = 1.0f / fmaxf(sqrtf(tot), 1e-12f);
    }
    __syncthreads();

    // normalize + relu + h store (bf16) + channel partials
    float csum[4] = {0.f,0.f,0.f,0.f};
    float csq [4] = {0.f,0.f,0.f,0.f};
    #pragma unroll
    for (int mt = 0; mt < 2; ++mt) {
        #pragma unroll
        for (int r = 0; r < 4; ++r) {
            int row = mt * 16 + quad * 4 + r;
            float rn = rnorm[row];
            unsigned short* hp = h + (r0g + row) * CC + cbg + l16;
            #pragma unroll
            for (int nt = 0; nt < 4; ++nt) {
                float v = fmaxf(acc[mt][nt][r] * rn, 0.0f);
                hp[nt * 16] = f2bf(v);
                csum[nt] += v;
                csq [nt] += v * v;
            }
        }
    }
    #pragma unroll
    for (int off = 16; off < 64; off <<= 1)
        #pragma unroll
        for (int nt = 0; nt < 4; ++nt) {
            csum[nt] += __shfl_xor(csum[nt], off, 64);
            csq [nt] += __shfl_xor(csq [nt], off, 64);
        }
    if (quad == 0 && p == 0) {
        #pragma unroll
        for (int nt = 0; nt < 4; ++nt) {
            int c = cbg + nt * 16 + l16;
            psum[(size_t)c * NBLK + bid] = csum[nt];
            psq [(size_t)c * NBLK + bid] = csq [nt];
        }
    }
}

// ---------------- K3: reduce BN partials (512 per channel) -> scale/shift
__global__ void k_stats(const float* __restrict__ psum, const float* __restrict__ psq,
                        const float* __restrict__ gamma, const float* __restrict__ beta,
                        float* __restrict__ ss) {
    __shared__ float ps[4], pq[4];
    int c = blockIdx.x, t = threadIdx.x;
    float s = psum[(size_t)c * NBLK + t] + psum[(size_t)c * NBLK + 256 + t];
    float q = psq [(size_t)c * NBLK + t] + psq [(size_t)c * NBLK + 256 + t];
    #pragma unroll
    for (int off = 32; off; off >>= 1) { s += __shfl_xor(s, off, 64); q += __shfl_xor(q, off, 64); }
    int w = t >> 6, lane = t & 63;
    if (lane == 0) { ps[w] = s; pq[w] = q; }
    __syncthreads();
    if (t == 0) {
        float S = ps[0] + ps[1] + ps[2] + ps[3];
        float Q = pq[0] + pq[1] + pq[2] + pq[3];
        const float inv = 1.0f / (float)MM;
        float mu  = S * inv;
        float var = fmaxf(Q * inv - mu * mu, 0.0f);
        float sc  = gamma[c] * rsqrtf(var + 1e-5f);
        ss[c]      = sc;
        ss[CC + c] = beta[c] - mu * sc;
    }
}

// ---------------- K4: BN apply, bf16 h -> fp32 out, 8 elems/thread
__global__ void k_apply(const unsigned short* __restrict__ h,
                        const float* __restrict__ ss,
                        float* __restrict__ out) {
    int gid = blockIdx.x * 256 + threadIdx.x;   // 8 elems/thread
    int c0 = (gid * 8) & (CC - 1);
    uint4 hv = ((const uint4*)h)[gid];          // 8 bf16
    const unsigned short* hs = (const unsigned short*)&hv;
    float4 sc0 = *(const float4*)(ss + c0);
    float4 sc1 = *(const float4*)(ss + c0 + 4);
    float4 sh0 = *(const float4*)(ss + CC + c0);
    float4 sh1 = *(const float4*)(ss + CC + c0 + 4);
    float4 o0, o1;
    o0.x = bf2f(hs[0]) * sc0.x + sh0.x;
    o0.y = bf2f(hs[1]) * sc0.y + sh0.y;
    o0.z = bf2f(hs[2]) * sc0.z + sh0.z;
    o0.w = bf2f(hs[3]) * sc0.w + sh0.w;
    o1.x = bf2f(hs[4]) * sc1.x + sh1.x;
    o1.y = bf2f(hs[5]) * sc1.y + sh1.y;
    o1.z = bf2f(hs[6]) * sc1.z + sh1.z;
    o1.w = bf2f(hs[7]) * sc1.w + sh1.w;
    ((float4*)out)[gid * 2]     = o0;
    ((float4*)out)[gid * 2 + 1] = o1;
}

extern "C" void kernel_launch(void* const* d_in, const int* in_sizes, int n_in,
                              void* d_out, int out_size, void* d_ws, size_t ws_size,
                              hipStream_t stream) {
    const float* x     = (const float*)d_in[0];
    const int*   idx   = (const int*)  d_in[1];
    const float* Wx_w  = (const float*)d_in[2];
    const float* Wx_b  = (const float*)d_in[3];
    const float* Wn_w  = (const float*)d_in[4];
    const float* Wn_b  = (const float*)d_in[5];
    const float* gamma = (const float*)d_in[6];
    const float* beta  = (const float*)d_in[7];
    float* out = (float*)d_out;

    char* p = (char*)d_ws;
    unsigned short* xb = (unsigned short*)p; p += (size_t)MM * FIN * 2;   // 8.4 MB
    unsigned short* Wc = (unsigned short*)p; p += (size_t)CC * FIN * 2;   // 256 KB
    float* bc          = (float*)p;          p += (size_t)CC * 4;         // 2 KB
    unsigned short* h  = (unsigned short*)p; p += (size_t)MM * CC * 2;    // 16.8 MB
    float* psum        = (float*)p;          p += (size_t)CC * NBLK * 4;  // 1 MB
    float* psq         = (float*)p;          p += (size_t)CC * NBLK * 4;  // 1 MB
    float* ss          = (float*)p;          p += (size_t)2 * CC * 4;     // 4 KB

    hipLaunchKernelGGL(k_prep,  dim3(2176), dim3(256), 0, stream,
                       Wx_w, Wx_b, Wn_w, Wn_b, x, Wc, bc, xb);
    hipLaunchKernelGGL(k_gemm,  dim3(NBLK), dim3(512), 0, stream, xb, idx, Wc, bc, h, psum, psq);
    hipLaunchKernelGGL(k_stats, dim3(CC),   dim3(256), 0, stream, psum, psq, gamma, beta, ss);
    hipLaunchKernelGGL(k_apply, dim3(4096), dim3(256), 0, stream, h, ss, out);
}